// Round 16
// baseline (180.126 us; speedup 1.0000x reference)
//
#include <hip/hip_runtime.h>

// B=4, N=M=4096, D=128.
// d_out (floats): match_mask [4*4096*4096] | pairs [16384] (as float) | top_dists [16384]
// ws fast path:
//   bytes [0, 131072):        x2 [16384] f32 | y2 [16384] f32
//   bytes [131072, 25296896): planes, 6 x PS elems bf16 (x:h,m,l then y:h,m,l)
//     32x32-fragment chunks: chunk idx (b*2+kh)*128 + t32 (t32=row>>5), 2048 elems (4KB):
//       [kc(4)][lane(64)][e(8)] holding in[b][t32*32+(lane&31)][kh*64+kc*16+(lane>>5)*8+e]
//   then pv [16384*2] f32 | pi [16384*2] i32
// Products: hh, hm, mh, mm, hl, lh via mfma_f32_32x32x16_bf16.
// Round-16: round-15 structure frozen; all global accesses via 32-bit element
// offsets from uniform bases (cuts 64-bit address VALU chains). Waits 2/18 kept.

typedef float  f32x4   __attribute__((ext_vector_type(4)));
typedef float  f32x16  __attribute__((ext_vector_type(16)));
typedef short  bf16x8  __attribute__((ext_vector_type(8)));

#define PS ((size_t)2097152)
#define PSU 2097152u

#define WAITVM_(N) asm volatile("s_waitcnt vmcnt(" #N ")" ::: "memory")
#define WAITVM(N)  WAITVM_(N)
#define BAR        __builtin_amdgcn_s_barrier()
#define FENCE      asm volatile("" ::: "memory")

__device__ __forceinline__ unsigned short f2bf(float x) {
    unsigned u = __float_as_uint(x);
    u += 0x7FFFu + ((u >> 16) & 1u);
    return (unsigned short)(u >> 16);
}
__device__ __forceinline__ float bf2f(unsigned short s) {
    return __uint_as_float(((unsigned)s) << 16);
}
__device__ __forceinline__ void gload_lds16(const void* g, void* l) {
    __builtin_amdgcn_global_load_lds(
        (const __attribute__((address_space(1))) void*)g,
        (__attribute__((address_space(3))) void*)l, 16, 0, 0);
}

// ---- split f32 -> 3 bf16 planes (32x32 fragment order) + fused row sum-of-squares ----
__global__ __launch_bounds__(256) void k_prep(const float* __restrict__ xd,
                                              const float* __restrict__ yd,
                                              unsigned short* __restrict__ pl,
                                              float* __restrict__ ws) {
    __shared__ float sm[4][16];
    int bid  = blockIdx.x;            // 0..2047
    int i    = bid >> 10;
    int b    = (bid >> 8) & 3;
    int rblk = bid & 255;             // 16-row block
    int tid  = threadIdx.x;
    int kb   = tid >> 6;              // 0..3 (32-k block)
    int l    = tid & 63;
    int lg4  = (l >> 4) & 3;
    int r    = rblk * 16 + (l & 15);
    int k0   = kb * 32 + lg4 * 8;
    const float* src = (i ? yd : xd) + ((size_t)(b * 4096 + r) * 128 + k0);
    float v[8];
    *reinterpret_cast<float4*>(v)     = *reinterpret_cast<const float4*>(src);
    *reinterpret_cast<float4*>(v + 4) = *reinterpret_cast<const float4*>(src + 4);
    bf16x8 hv, mv, lv;
    float s = 0.f;
    #pragma unroll
    for (int e = 0; e < 8; ++e) {
        float x = v[e];
        s = fmaf(x, x, s);
        unsigned short h  = f2bf(x);
        float r1 = x - bf2f(h);
        unsigned short m  = f2bf(r1);
        float r2 = r1 - bf2f(m);
        unsigned short lo = f2bf(r2);
        hv[e] = (short)h; mv[e] = (short)m; lv[e] = (short)lo;
    }
    int kh   = kb >> 1;
    int kc2  = (kb & 1) * 2 + (lg4 >> 1);
    int land = (r & 31) + ((lg4 & 1) << 5);
    size_t base = ((size_t)((b * 2 + kh) * 128 + (rblk >> 1))) * 2048
                + (size_t)(kc2 * 64 + land) * 8;
    unsigned short* dst = pl + (size_t)(i * 3) * PS;
    *reinterpret_cast<bf16x8*>(dst + base)          = hv;
    *reinterpret_cast<bf16x8*>(dst + base + PS)     = mv;
    *reinterpret_cast<bf16x8*>(dst + base + 2 * PS) = lv;
    s += __shfl_xor(s, 16);
    s += __shfl_xor(s, 32);
    if (l < 16) sm[kb][l] = s;
    __syncthreads();
    if (tid < 16) {
        float t = sm[0][tid] + sm[1][tid] + sm[2][tid] + sm[3][tid];
        ws[(i ? 16384 : 0) + b * 4096 + rblk * 16 + tid] = t;
    }
}

// ---- main: 64-row blocks, 2/CU, 32x32 MFMA, 2-phase/ct, 32-bit offsets ----
__global__ __launch_bounds__(256, 2) void k_gemm(const float* __restrict__ mask,
                                                 const float* __restrict__ ws,
                                                 const unsigned short* __restrict__ pl,
                                                 float* __restrict__ out,
                                                 float* __restrict__ pv,
                                                 int* __restrict__ pi) {
    __shared__ __align__(16) unsigned short Ab[2][2][4096];  // 32 KiB: A h,m per kh (64 rows)
    __shared__ __align__(16) unsigned short Bp[2][3][4096];  // 48 KiB: [slot][plane h,m,l]

    const int bid = blockIdx.x;        // 512 blocks = 2/CU
    const int xcd = bid & 7;
    const int b   = xcd >> 1;          // batch pinned per XCD pair
    const int ch  = xcd & 1;           // col half (2048 cols)
    const int rt  = bid >> 3;          // 64-row tile 0..63
    const int tid = threadIdx.x;
    const int w   = tid >> 6, l = tid & 63;
    const int wr  = w >> 1, wc = w & 1;     // 2x2 waves: 32 rows x 32 cols per col-step
    const int l31 = l & 31, lg1 = l >> 5;
    const int g0  = b * 4096 + rt * 64;

    float x2r[16];
    #pragma unroll
    for (int rg = 0; rg < 16; ++rg)
        x2r[rg] = ws[g0 + wr * 32 + (rg & 3) + 8 * (rg >> 2) + 4 * lg1];

    // uniform 32-bit bases (element offsets)
    const unsigned mbase = (unsigned)(g0 + wr * 32 + 4 * lg1) * 4096u
                         + (unsigned)(ch * 2048 + wc * 32 + l31);
    const unsigned ybase = 16384u + (unsigned)(b * 4096 + ch * 2048 + wc * 32 + l31);
    const unsigned zbase = (unsigned)(g0 + (tid >> 4)) * 4096u
                         + (unsigned)(ch * 2048 + ((tid & 15) << 2));

    // ---- prologue: A h,m -> LDS (8KB per (pl,kh)); A-l -> regs; B ct0,kh0 -> slot0 ----
    #pragma unroll
    for (int kh = 0; kh < 2; ++kh)
        #pragma unroll
        for (int ap = 0; ap < 2; ++ap) {
            const unsigned short* Ac = pl + (size_t)ap * PS
                + (((size_t)((b * 2 + kh) * 128 + rt * 2)) << 11);
            gload_lds16((const char*)Ac + tid * 16,
                        (char*)(&Ab[kh][ap][0]) + tid * 16);
            gload_lds16((const char*)Ac + 4096 + tid * 16,
                        (char*)(&Ab[kh][ap][0]) + 4096 + tid * 16);
        }
    bf16x8 Al[2][4];
    #pragma unroll
    for (int kh = 0; kh < 2; ++kh) {
        const unsigned short* Ac = pl + (size_t)2 * PS
            + (((size_t)((b * 2 + kh) * 128 + rt * 2 + wr)) << 11);
        #pragma unroll
        for (int kc = 0; kc < 4; ++kc)
            Al[kh][kc] = *reinterpret_cast<const bf16x8*>(Ac + (kc * 64 + l) * 8);
    }

#define STAGE_B(CT, KH, SLOT) do {                                                \
    const unsigned sb_ = (unsigned)(((b * 2 + (KH)) * 128 + ch * 64 + (CT) * 2) << 11) \
                       + (unsigned)(tid * 8);                                     \
    _Pragma("unroll") for (int bp_ = 0; bp_ < 3; ++bp_) {                         \
        gload_lds16(pl + ((size_t)(3 + bp_) * PS) + sb_,                          \
                    (char*)(&Bp[SLOT][bp_][0]) + tid * 16);                       \
        gload_lds16(pl + ((size_t)(3 + bp_) * PS) + sb_ + 2048u,                  \
                    (char*)(&Bp[SLOT][bp_][0]) + 4096 + tid * 16);                \
    }                                                                             \
} while (0)

#define MLOAD16(CT) do {                                                          \
    const unsigned mb_ = mbase + (unsigned)((CT) * 64);                           \
    pm[0]  = mask[mb_];            pm[1]  = mask[mb_ + 1u * 4096u];               \
    pm[2]  = mask[mb_ + 2u * 4096u];  pm[3]  = mask[mb_ + 3u * 4096u];            \
    pm[4]  = mask[mb_ + 8u * 4096u];  pm[5]  = mask[mb_ + 9u * 4096u];            \
    pm[6]  = mask[mb_ + 10u * 4096u]; pm[7]  = mask[mb_ + 11u * 4096u];           \
    pm[8]  = mask[mb_ + 16u * 4096u]; pm[9]  = mask[mb_ + 17u * 4096u];           \
    pm[10] = mask[mb_ + 18u * 4096u]; pm[11] = mask[mb_ + 19u * 4096u];           \
    pm[12] = mask[mb_ + 24u * 4096u]; pm[13] = mask[mb_ + 25u * 4096u];           \
    pm[14] = mask[mb_ + 26u * 4096u]; pm[15] = mask[mb_ + 27u * 4096u];           \
    yv = ws[ybase + (unsigned)((CT) * 64)];                                       \
} while (0)

#define ZST(CT, I) do {                                                           \
    const f32x4 z_ = (f32x4){0.f, 0.f, 0.f, 0.f};                                 \
    *reinterpret_cast<f32x4*>(out + zbase                                         \
        + (unsigned)((I) * 16 * 4096 + (CT) * 64)) = z_;                          \
} while (0)

// per-phase: 4 kc x { A h,m ds_reads + A-l reg; B h,m,l ds_reads; 6 MFMA } = 24 MFMA
#define COMPUTE(KH, SLOT) do {                                                    \
    __builtin_amdgcn_s_setprio(1);                                                \
    _Pragma("unroll") for (int kc = 0; kc < 4; ++kc) {                            \
        const int fa = wr * 2048 + kc * 512 + l * 8;                              \
        bf16x8 Ah_ = *reinterpret_cast<const bf16x8*>(&Ab[KH][0][fa]);            \
        bf16x8 Am_ = *reinterpret_cast<const bf16x8*>(&Ab[KH][1][fa]);            \
        bf16x8 Al_ = Al[KH][kc];                                                  \
        const int fb = wc * 2048 + kc * 512 + l * 8;                              \
        bf16x8 Bh_ = *reinterpret_cast<const bf16x8*>(&Bp[SLOT][0][fb]);          \
        bf16x8 Bm_ = *reinterpret_cast<const bf16x8*>(&Bp[SLOT][1][fb]);          \
        bf16x8 Bl_ = *reinterpret_cast<const bf16x8*>(&Bp[SLOT][2][fb]);          \
        acc = __builtin_amdgcn_mfma_f32_32x32x16_bf16(Ah_, Bh_, acc, 0, 0, 0);    \
        acc = __builtin_amdgcn_mfma_f32_32x32x16_bf16(Am_, Bh_, acc, 0, 0, 0);    \
        acc = __builtin_amdgcn_mfma_f32_32x32x16_bf16(Al_, Bh_, acc, 0, 0, 0);    \
        acc = __builtin_amdgcn_mfma_f32_32x32x16_bf16(Ah_, Bm_, acc, 0, 0, 0);    \
        acc = __builtin_amdgcn_mfma_f32_32x32x16_bf16(Am_, Bm_, acc, 0, 0, 0);    \
        acc = __builtin_amdgcn_mfma_f32_32x32x16_bf16(Ah_, Bl_, acc, 0, 0, 0);    \
    }                                                                             \
    __builtin_amdgcn_s_setprio(0);                                                \
} while (0)

    float pm[16], yv;
    f32x16 acc;

    STAGE_B(0, 0, 0);
    WAITVM(0);
    BAR;

    const double INITD = __hiloint2double(0x7f7fffff, 0);
    double bv[16];
    #pragma unroll
    for (int q = 0; q < 16; ++q) bv[q] = INITD;

    #pragma unroll 1
    for (int ct = 0; ct < 32; ++ct) {
        const int ctn = (ct < 31) ? ct + 1 : 31;

        // ---- phase kh0: compute slot0; stage kh1 -> slot1; masks for ct ----
        WAITVM(2); BAR;                 // retire stage(s0); leave prev 2 ZSTs
        #pragma unroll
        for (int e = 0; e < 16; ++e) acc[e] = 0.f;
        STAGE_B(ct, 1, 1);
        FENCE;
        MLOAD16(ct);
        FENCE;
        ZST(ct, 0); ZST(ct, 1);
        COMPUTE(0, 0);

        // ---- phase kh1: compute slot1; stage next kh0 -> slot0; epilogue ----
        WAITVM(18); BAR;                // retire stage(s1); leave pm16+yv1+zst2 -> 18? (pm17+zst2 minus1 conservative ok)
        STAGE_B(ctn, 0, 0);
        FENCE;
        ZST(ct, 2); ZST(ct, 3);
        COMPUTE(1, 1);

        // epilogue: packed (dist,col) f64 argmin (pm/yv via compiler auto-wait)
        {
            const int c = ch * 2048 + ct * 64 + wc * 32 + l31;
            #pragma unroll
            for (int rg = 0; rg < 16; ++rg) {
                float d2 = fmaf(acc[rg], -2.0f, x2r[rg]) + yv;
                float d  = sqrtf(fmaxf(d2, 0.0f)) * pm[rg];
                double pk = __hiloint2double(__float_as_int(d), c);
                bv[rg] = fmin(bv[rg], pk);
            }
        }
    }
#undef STAGE_B
#undef MLOAD16
#undef ZST
#undef COMPUTE

    WAITVM(0);

    // ---- reduce across 32 col-lanes (packed min), then 2 col-waves via LDS ----
    #pragma unroll
    for (int off = 1; off < 32; off <<= 1) {
        #pragma unroll
        for (int q = 0; q < 16; ++q)
            bv[q] = fmin(bv[q], __shfl_xor(bv[q], off));
    }
    __syncthreads();                    // B LDS free; overlay candidates
    double* cd = reinterpret_cast<double*>(&Bp[0][0][0]);   // [64][2]
    if (l31 == 0) {
        #pragma unroll
        for (int rg = 0; rg < 16; ++rg) {
            int rowl = wr * 32 + (rg & 3) + 8 * (rg >> 2) + 4 * lg1;
            cd[rowl * 2 + wc] = bv[rg];
        }
    }
    __syncthreads();
    if (tid < 64) {
        double v = fmin(cd[tid * 2], cd[tid * 2 + 1]);
        int grow = g0 + tid;
        pv[grow * 2 + ch] = __int_as_float(__double2hiint(v));
        pi[grow * 2 + ch] = __double2loint(v);
    }
}

__global__ __launch_bounds__(256) void k_fin(const float* __restrict__ pv,
                                             const int* __restrict__ pi,
                                             float* __restrict__ out) {
    int t = blockIdx.x * 256 + threadIdx.x;   // row 0..16383
    float v0 = pv[t * 2], v1 = pv[t * 2 + 1];
    int   i0 = pi[t * 2], i1 = pi[t * 2 + 1];
    bool take1 = (v1 < v0) || (v1 == v0 && i1 < i0);
    float v  = take1 ? v1 : v0;
    int   ix = take1 ? i1 : i0;
    out[67108864 + t]         = (float)ix;            // pairs
    out[67108864 + 16384 + t] = v;                    // top_dists
    out[(size_t)t * 4096 + (size_t)ix] = 1.0f;        // one-hot
}

// ================= fallback path (needs only 384 KB ws) =================
__global__ __launch_bounds__(256) void k_rowsq(const float* __restrict__ xd,
                                               const float* __restrict__ yd,
                                               float* __restrict__ ws) {
    int tid  = threadIdx.x;
    int wid  = tid >> 6, lane = tid & 63;
    int gr   = blockIdx.x * 4 + wid;
    const float* src = (gr < 16384) ? (xd + (size_t)gr * 128)
                                    : (yd + (size_t)(gr - 16384) * 128);
    float2 v = reinterpret_cast<const float2*>(src)[lane];
    float s  = v.x * v.x + v.y * v.y;
    for (int off = 32; off > 0; off >>= 1) s += __shfl_down(s, off);
    if (lane == 0) ws[gr] = s;
}

__global__ __launch_bounds__(256, 1) void k_main_fb(const float* __restrict__ xd,
                                                    const float* __restrict__ yd,
                                                    const float* __restrict__ mask,
                                                    const float* __restrict__ ws,
                                                    float* __restrict__ pvals,
                                                    int* __restrict__ pidx,
                                                    float* __restrict__ mm) {
    __shared__ __align__(16) float Xs[128 * 128];
    __shared__ __align__(16) float Ys[128 * 128];
    const int bid  = blockIdx.x;
    const int mh   = bid & 1;
    const int rb   = (bid >> 1) & 31;
    const int b    = bid >> 6;
    const int tid  = threadIdx.x;
    const int ty   = tid >> 4;
    const int tx   = tid & 15;
    const int row0 = rb * 128;
    const int m0   = mh * 2048;
    {
        const float4 z = make_float4(0.f, 0.f, 0.f, 0.f);
        size_t base = ((size_t)(b * 4096 + row0)) * 4096 + (size_t)m0;
        for (int r = 0; r < 128; ++r) {
            float4* p = reinterpret_cast<float4*>(mm + base + (size_t)r * 4096);
            p[tid] = z; p[tid + 256] = z;
        }
    }
    {
        int lrow = tid >> 5, slot = tid & 31;
        for (int p = 0; p < 16; ++p) {
            int row  = p * 8 + lrow;
            float4 v = reinterpret_cast<const float4*>(
                           xd + ((size_t)(b * 4096 + row0 + row)) * 128)[slot];
            int ss = slot ^ (row & 31);
            *reinterpret_cast<float4*>(&Xs[row * 128 + (ss << 2)]) = v;
        }
    }
    float x2r[8];
    #pragma unroll
    for (int i = 0; i < 8; ++i) x2r[i] = ws[b * 4096 + row0 + ty * 8 + i];
    const float* y2g = ws + 16384 + b * 4096;
    float bv[8]; int bi[8];
    #pragma unroll
    for (int i = 0; i < 8; ++i) { bv[i] = 3.4e38f; bi[i] = 0; }
    __syncthreads();
    for (int tile = 0; tile < 16; ++tile) {
        const int mbase = m0 + tile * 128;
        {
            int lrow = tid >> 5, slot = tid & 31;
            for (int p = 0; p < 16; ++p) {
                int row  = p * 8 + lrow;
                float4 v = reinterpret_cast<const float4*>(
                               yd + ((size_t)(b * 4096 + mbase + row)) * 128)[slot];
                int ss = slot ^ (row & 31);
                *reinterpret_cast<float4*>(&Ys[row * 128 + (ss << 2)]) = v;
            }
        }
        __syncthreads();
        float acc[8][8];
        #pragma unroll
        for (int i = 0; i < 8; ++i)
            #pragma unroll
            for (int jj = 0; jj < 8; ++jj) acc[i][jj] = 0.0f;
        #pragma unroll 4
        for (int ks = 0; ks < 32; ++ks) {
            float4 bf[8];
            #pragma unroll
            for (int jj = 0; jj < 8; ++jj) {
                int c = jj * 16 + tx;
                bf[jj] = *reinterpret_cast<const float4*>(&Ys[c * 128 + ((ks ^ (c & 31)) << 2)]);
            }
            #pragma unroll
            for (int i = 0; i < 8; ++i) {
                int r = ty * 8 + i;
                float4 a = *reinterpret_cast<const float4*>(&Xs[r * 128 + ((ks ^ (r & 31)) << 2)]);
                #pragma unroll
                for (int jj = 0; jj < 8; ++jj) {
                    acc[i][jj] = fmaf(a.x, bf[jj].x, acc[i][jj]);
                    acc[i][jj] = fmaf(a.y, bf[jj].y, acc[i][jj]);
                    acc[i][jj] = fmaf(a.z, bf[jj].z, acc[i][jj]);
                    acc[i][jj] = fmaf(a.w, bf[jj].w, acc[i][jj]);
                }
            }
        }
        float y2v[8];
        #pragma unroll
        for (int jj = 0; jj < 8; ++jj) y2v[jj] = y2g[mbase + jj * 16 + tx];
        #pragma unroll
        for (int i = 0; i < 8; ++i) {
            int r = ty * 8 + i;
            const float* mr = mask + ((size_t)(b * 4096 + row0 + r)) * 4096;
            #pragma unroll
            for (int jj = 0; jj < 8; ++jj) {
                int   m  = mbase + jj * 16 + tx;
                float d2 = x2r[i] + y2v[jj] - 2.0f * acc[i][jj];
                float d  = sqrtf(fmaxf(d2, 0.0f)) * mr[m];
                if (d < bv[i]) { bv[i] = d; bi[i] = m; }
            }
        }
        __syncthreads();
    }
    float* candv = Xs;
    int*   candi = reinterpret_cast<int*>(Xs + 2048);
    #pragma unroll
    for (int i = 0; i < 8; ++i) {
        int r = ty * 8 + i;
        candv[r * 16 + tx] = bv[i];
        candi[r * 16 + tx] = bi[i];
    }
    __syncthreads();
    if (tid < 128) {
        int   r  = tid;
        float v  = candv[r * 16];
        int   ix = candi[r * 16];
        for (int t = 1; t < 16; ++t) {
            float v2 = candv[r * 16 + t];
            int   i2 = candi[r * 16 + t];
            if (v2 < v || (v2 == v && i2 < ix)) { v = v2; ix = i2; }
        }
        int grow = b * 4096 + row0 + r;
        pvals[grow * 2 + mh] = v;
        pidx [grow * 2 + mh] = ix;
    }
}

__global__ __launch_bounds__(256) void k_fin_fb(const float* __restrict__ pvals,
                                                const int* __restrict__ pidx,
                                                float* __restrict__ out) {
    int t = blockIdx.x * 256 + threadIdx.x;
    float v0 = pvals[t * 2], v1 = pvals[t * 2 + 1];
    int   i0 = pidx [t * 2], i1 = pidx [t * 2 + 1];
    bool take1 = (v1 < v0) || (v1 == v0 && i1 < i0);
    float v  = take1 ? v1 : v0;
    int   ix = take1 ? i1 : i0;
    out[67108864 + t]         = (float)ix;
    out[67108864 + 16384 + t] = v;
    out[(size_t)t * 4096 + (size_t)ix] = 1.0f;
}

extern "C" void kernel_launch(void* const* d_in, const int* in_sizes, int n_in,
                              void* d_out, int out_size, void* d_ws, size_t ws_size,
                              hipStream_t stream) {
    const float* xd   = (const float*)d_in[0];
    const float* yd   = (const float*)d_in[1];
    const float* mask = (const float*)d_in[2];
    float* out = (float*)d_out;
    float* wsf = (float*)d_ws;

    const size_t need = 131072 + 6 * PS * 2 + 262144;   // 25,559,040
    if (ws_size >= need) {
        unsigned short* pl = (unsigned short*)((char*)d_ws + 131072);
        float* pv = (float*)((char*)d_ws + 131072 + 6 * PS * 2);
        int*   pi = (int*)  ((char*)d_ws + 131072 + 6 * PS * 2 + 131072);
        k_prep <<<2048, 256, 0, stream>>>(xd, yd, pl, wsf);
        k_gemm <<<512,  256, 0, stream>>>(mask, wsf, pl, out, pv, pi);
        k_fin  <<<64,   256, 0, stream>>>(pv, pi, out);
    } else {
        float* pvals = wsf + 32768;
        int*   pidx  = (int*)(wsf + 65536);
        k_rowsq  <<<8192, 256, 0, stream>>>(xd, yd, wsf);
        k_main_fb<<<256,  256, 0, stream>>>(xd, yd, mask, wsf, pvals, pidx, out);
        k_fin_fb <<<64,   256, 0, stream>>>(pvals, pidx, out);
    }
}

// Round 17
// 174.887 us; speedup vs baseline: 1.0300x; 1.0300x over previous
//
#include <hip/hip_runtime.h>

// B=4, N=M=4096, D=128.
// d_out (floats): match_mask [4*4096*4096] | pairs [16384] (as float) | top_dists [16384]
// ws fast path:
//   bytes [0, 131072):        x2 [16384] f32 | y2 [16384] f32
//   bytes [131072, 25296896): planes, 6 x PS elems bf16 (x:h,m,l then y:h,m,l)
//     32x32-fragment chunks: chunk idx (b*2+kh)*128 + t32 (t32=row>>5), 2048 elems (4KB):
//       [kc(4)][lane(64)][e(8)] holding in[b][t32*32+(lane&31)][kh*64+kc*16+(lane>>5)*8+e]
//   then pv [16384*4] f32 | pi [16384*4] i32
// Products: hh, hm, mh, mm, hl, lh via mfma_f32_32x32x16_bf16.
// Round-17: A entirely in registers (96 VGPR: 3 planes x 2kh x 4kc per wave's 32 rows);
// LDS = B only (2 slots x 2kh x 3 planes x 4KB = 48 KiB) -> 2 blocks/CU kept.
// Merged single-phase ct (32 cols): ONE WAITVM(4)+BAR per ct, stage has full-ct flight,
// FIFO order [pm17][stage6][zst4] so the epilogue's pm auto-wait never drains the stage.

typedef float  f32x4   __attribute__((ext_vector_type(4)));
typedef float  f32x16  __attribute__((ext_vector_type(16)));
typedef short  bf16x8  __attribute__((ext_vector_type(8)));

#define PS ((size_t)2097152)

#define WAITVM_(N) asm volatile("s_waitcnt vmcnt(" #N ")" ::: "memory")
#define WAITVM(N)  WAITVM_(N)
#define BAR        __builtin_amdgcn_s_barrier()
#define FENCE      asm volatile("" ::: "memory")

__device__ __forceinline__ unsigned short f2bf(float x) {
    unsigned u = __float_as_uint(x);
    u += 0x7FFFu + ((u >> 16) & 1u);
    return (unsigned short)(u >> 16);
}
__device__ __forceinline__ float bf2f(unsigned short s) {
    return __uint_as_float(((unsigned)s) << 16);
}
__device__ __forceinline__ void gload_lds16(const void* g, void* l) {
    __builtin_amdgcn_global_load_lds(
        (const __attribute__((address_space(1))) void*)g,
        (__attribute__((address_space(3))) void*)l, 16, 0, 0);
}

// ---- split f32 -> 3 bf16 planes (32x32 fragment order) + fused row sum-of-squares ----
__global__ __launch_bounds__(256) void k_prep(const float* __restrict__ xd,
                                              const float* __restrict__ yd,
                                              unsigned short* __restrict__ pl,
                                              float* __restrict__ ws) {
    __shared__ float sm[4][16];
    int bid  = blockIdx.x;            // 0..2047
    int i    = bid >> 10;
    int b    = (bid >> 8) & 3;
    int rblk = bid & 255;             // 16-row block
    int tid  = threadIdx.x;
    int kb   = tid >> 6;              // 0..3 (32-k block)
    int l    = tid & 63;
    int lg4  = (l >> 4) & 3;
    int r    = rblk * 16 + (l & 15);
    int k0   = kb * 32 + lg4 * 8;
    const float* src = (i ? yd : xd) + ((size_t)(b * 4096 + r) * 128 + k0);
    float v[8];
    *reinterpret_cast<float4*>(v)     = *reinterpret_cast<const float4*>(src);
    *reinterpret_cast<float4*>(v + 4) = *reinterpret_cast<const float4*>(src + 4);
    bf16x8 hv, mv, lv;
    float s = 0.f;
    #pragma unroll
    for (int e = 0; e < 8; ++e) {
        float x = v[e];
        s = fmaf(x, x, s);
        unsigned short h  = f2bf(x);
        float r1 = x - bf2f(h);
        unsigned short m  = f2bf(r1);
        float r2 = r1 - bf2f(m);
        unsigned short lo = f2bf(r2);
        hv[e] = (short)h; mv[e] = (short)m; lv[e] = (short)lo;
    }
    int kh   = kb >> 1;
    int kc2  = (kb & 1) * 2 + (lg4 >> 1);
    int land = (r & 31) + ((lg4 & 1) << 5);
    size_t base = ((size_t)((b * 2 + kh) * 128 + (rblk >> 1))) * 2048
                + (size_t)(kc2 * 64 + land) * 8;
    unsigned short* dst = pl + (size_t)(i * 3) * PS;
    *reinterpret_cast<bf16x8*>(dst + base)          = hv;
    *reinterpret_cast<bf16x8*>(dst + base + PS)     = mv;
    *reinterpret_cast<bf16x8*>(dst + base + 2 * PS) = lv;
    s += __shfl_xor(s, 16);
    s += __shfl_xor(s, 32);
    if (l < 16) sm[kb][l] = s;
    __syncthreads();
    if (tid < 16) {
        float t = sm[0][tid] + sm[1][tid] + sm[2][tid] + sm[3][tid];
        ws[(i ? 16384 : 0) + b * 4096 + rblk * 16 + tid] = t;
    }
}

// ---- main: A-in-regs, B-only LDS, merged single-phase ct, 2 blocks/CU ----
__global__ __launch_bounds__(256, 2) void k_gemm(const float* __restrict__ mask,
                                                 const float* __restrict__ ws,
                                                 const unsigned short* __restrict__ pl,
                                                 float* __restrict__ out,
                                                 float* __restrict__ pv,
                                                 int* __restrict__ pi) {
    __shared__ __align__(16) unsigned short Bp[2][2][3][2048];  // 48 KiB

    const int bid = blockIdx.x;        // 512 blocks = 2/CU
    const int xcd = bid & 7;
    const int b   = xcd >> 1;          // batch pinned per XCD pair
    const int cqh = xcd & 1;           // quarter-pair
    const int sub = bid >> 3;          // 0..63
    const int cq  = cqh * 2 + (sub & 1);   // col quarter (1024 cols)
    const int rt  = sub >> 1;          // 128-row tile 0..31
    const int tid = threadIdx.x;
    const int w   = tid >> 6, l = tid & 63;   // 4 row-waves of 32 rows
    const int l31 = l & 31, lg1 = l >> 5;
    const int g0  = b * 4096 + rt * 128;
    const int col0 = cq * 1024;

    // ---- A fragments in registers: [plane][kh][kc], wave w owns rows g0+w*32.. ----
    bf16x8 Af[3][2][4];
    #pragma unroll
    for (int p = 0; p < 3; ++p)
        #pragma unroll
        for (int kh = 0; kh < 2; ++kh) {
            const unsigned short* Ac = pl + (size_t)p * PS
                + (((size_t)((b * 2 + kh) * 128 + rt * 4 + w)) << 11);
            #pragma unroll
            for (int kc = 0; kc < 4; ++kc)
                Af[p][kh][kc] = *reinterpret_cast<const bf16x8*>(Ac + (kc * 64 + l) * 8);
        }

    float x2r[16];
    #pragma unroll
    for (int rg = 0; rg < 16; ++rg)
        x2r[rg] = ws[g0 + w * 32 + (rg & 3) + 8 * (rg >> 2) + 4 * lg1];

    const unsigned mbase = (unsigned)(g0 + w * 32 + 4 * lg1) * 4096u
                         + (unsigned)(col0 + l31);
    const unsigned ybase = 16384u + (unsigned)(b * 4096 + col0 + l31);
    const unsigned zbase = (unsigned)(g0 + (tid >> 3)) * 4096u
                         + (unsigned)(col0 + ((tid & 7) << 2));

#define STAGE(CT, SLOT) do {                                                      \
    _Pragma("unroll") for (int kh_ = 0; kh_ < 2; ++kh_)                           \
    _Pragma("unroll") for (int p_ = 0; p_ < 3; ++p_) {                            \
        const unsigned short* Bc_ = pl + (size_t)(3 + p_) * PS                    \
            + (((size_t)((b * 2 + kh_) * 128 + cq * 32 + (CT))) << 11);           \
        gload_lds16((const char*)Bc_ + tid * 16,                                  \
                    (char*)(&Bp[SLOT][kh_][p_][0]) + tid * 16);                   \
    }                                                                             \
} while (0)

#define MLOAD(CT) do {                                                            \
    const unsigned mb_ = mbase + (unsigned)((CT) * 32);                           \
    _Pragma("unroll") for (int rg_ = 0; rg_ < 16; ++rg_) {                        \
        const unsigned ro_ = (unsigned)(((rg_ & 3) + 8 * (rg_ >> 2)) * 4096);     \
        pm[rg_] = mask[mb_ + ro_];                                                \
    }                                                                             \
    yv = ws[ybase + (unsigned)((CT) * 32)];                                       \
} while (0)

#define ZST(CT, I) do {                                                           \
    const f32x4 z_ = (f32x4){0.f, 0.f, 0.f, 0.f};                                 \
    *reinterpret_cast<f32x4*>(out + zbase                                         \
        + (unsigned)((I) * 32 * 4096 + (CT) * 32)) = z_;                          \
} while (0)

// 2 kh x 4 kc x 6 MFMA = 48 MFMA(32x32) per ct per wave; B from LDS, A from regs.
#define COMPUTE(SLOT) do {                                                        \
    __builtin_amdgcn_s_setprio(1);                                                \
    _Pragma("unroll") for (int kh_ = 0; kh_ < 2; ++kh_)                           \
    _Pragma("unroll") for (int kc_ = 0; kc_ < 4; ++kc_) {                         \
        const int fb_ = (kc_ * 64 + l) * 8;                                       \
        bf16x8 Bh_ = *reinterpret_cast<const bf16x8*>(&Bp[SLOT][kh_][0][fb_]);    \
        bf16x8 Bm_ = *reinterpret_cast<const bf16x8*>(&Bp[SLOT][kh_][1][fb_]);    \
        bf16x8 Bl_ = *reinterpret_cast<const bf16x8*>(&Bp[SLOT][kh_][2][fb_]);    \
        acc = __builtin_amdgcn_mfma_f32_32x32x16_bf16(Af[0][kh_][kc_], Bh_, acc, 0, 0, 0); \
        acc = __builtin_amdgcn_mfma_f32_32x32x16_bf16(Af[1][kh_][kc_], Bh_, acc, 0, 0, 0); \
        acc = __builtin_amdgcn_mfma_f32_32x32x16_bf16(Af[2][kh_][kc_], Bh_, acc, 0, 0, 0); \
        acc = __builtin_amdgcn_mfma_f32_32x32x16_bf16(Af[0][kh_][kc_], Bm_, acc, 0, 0, 0); \
        acc = __builtin_amdgcn_mfma_f32_32x32x16_bf16(Af[1][kh_][kc_], Bm_, acc, 0, 0, 0); \
        acc = __builtin_amdgcn_mfma_f32_32x32x16_bf16(Af[0][kh_][kc_], Bl_, acc, 0, 0, 0); \
    }                                                                             \
    __builtin_amdgcn_s_setprio(0);                                                \
} while (0)

#define EPI(CT) do {                                                              \
    const int c_ = col0 + (CT) * 32 + l31;                                        \
    _Pragma("unroll") for (int rg_ = 0; rg_ < 16; ++rg_) {                        \
        float d2 = fmaf(acc[rg_], -2.0f, x2r[rg_]) + yv;                          \
        float d  = sqrtf(fmaxf(d2, 0.0f)) * pm[rg_];                              \
        double pk = __hiloint2double(__float_as_int(d), c_);                      \
        bv[rg_] = fmin(bv[rg_], pk);                                              \
    }                                                                             \
} while (0)

    float pm[16], yv;
    f32x16 acc;

    STAGE(0, 0);
    WAITVM(0);
    BAR;

    const double INITD = __hiloint2double(0x7f7fffff, 0);
    double bv[16];
    #pragma unroll
    for (int q = 0; q < 16; ++q) bv[q] = INITD;

    #pragma unroll 1
    for (int ct = 0; ct < 32; ++ct) {
        const int ctn = (ct < 31) ? ct + 1 : 31;

        WAITVM(4); BAR;                 // retire this ct's stage (full-ct flight); leave zst4
        #pragma unroll
        for (int e = 0; e < 16; ++e) acc[e] = 0.f;
        MLOAD(ct);                      // pm17: flight = the 48-MFMA compute below
        FENCE;
        STAGE(ctn, (ct + 1) & 1);       // stage6: flight = compute + epilogue + next top
        FENCE;
        ZST(ct, 0); ZST(ct, 1); ZST(ct, 2); ZST(ct, 3);
        COMPUTE(ct & 1);
        EPI(ct);                        // pm auto-wait retires pm17 only (stage6+zst4 fly)
    }
#undef STAGE
#undef MLOAD
#undef ZST
#undef COMPUTE
#undef EPI

    WAITVM(0);

    // ---- reduce across 32 col-lanes (packed min); waves own disjoint rows ----
    #pragma unroll
    for (int off = 1; off < 32; off <<= 1) {
        #pragma unroll
        for (int q = 0; q < 16; ++q)
            bv[q] = fmin(bv[q], __shfl_xor(bv[q], off));
    }
    if (l31 == 0) {
        #pragma unroll
        for (int rg = 0; rg < 16; ++rg) {
            int grow = g0 + w * 32 + (rg & 3) + 8 * (rg >> 2) + 4 * lg1;
            pv[grow * 4 + cq] = __int_as_float(__double2hiint(bv[rg]));
            pi[grow * 4 + cq] = __double2loint(bv[rg]);
        }
    }
}

__global__ __launch_bounds__(256) void k_fin(const float* __restrict__ pv,
                                             const int* __restrict__ pi,
                                             float* __restrict__ out) {
    int t = blockIdx.x * 256 + threadIdx.x;   // row 0..16383
    float v  = pv[t * 4];
    int   ix = pi[t * 4];
    #pragma unroll
    for (int q = 1; q < 4; ++q) {
        float v2 = pv[t * 4 + q];
        int   i2 = pi[t * 4 + q];
        if (v2 < v || (v2 == v && i2 < ix)) { v = v2; ix = i2; }
    }
    out[67108864 + t]         = (float)ix;            // pairs
    out[67108864 + 16384 + t] = v;                    // top_dists
    out[(size_t)t * 4096 + (size_t)ix] = 1.0f;        // one-hot
}

// ================= fallback path (needs only 384 KB ws) =================
__global__ __launch_bounds__(256) void k_rowsq(const float* __restrict__ xd,
                                               const float* __restrict__ yd,
                                               float* __restrict__ ws) {
    int tid  = threadIdx.x;
    int wid  = tid >> 6, lane = tid & 63;
    int gr   = blockIdx.x * 4 + wid;
    const float* src = (gr < 16384) ? (xd + (size_t)gr * 128)
                                    : (yd + (size_t)(gr - 16384) * 128);
    float2 v = reinterpret_cast<const float2*>(src)[lane];
    float s  = v.x * v.x + v.y * v.y;
    for (int off = 32; off > 0; off >>= 1) s += __shfl_down(s, off);
    if (lane == 0) ws[gr] = s;
}

__global__ __launch_bounds__(256, 1) void k_main_fb(const float* __restrict__ xd,
                                                    const float* __restrict__ yd,
                                                    const float* __restrict__ mask,
                                                    const float* __restrict__ ws,
                                                    float* __restrict__ pvals,
                                                    int* __restrict__ pidx,
                                                    float* __restrict__ mm) {
    __shared__ __align__(16) float Xs[128 * 128];
    __shared__ __align__(16) float Ys[128 * 128];
    const int bid  = blockIdx.x;
    const int mh   = bid & 1;
    const int rb   = (bid >> 1) & 31;
    const int b    = bid >> 6;
    const int tid  = threadIdx.x;
    const int ty   = tid >> 4;
    const int tx   = tid & 15;
    const int row0 = rb * 128;
    const int m0   = mh * 2048;
    {
        const float4 z = make_float4(0.f, 0.f, 0.f, 0.f);
        size_t base = ((size_t)(b * 4096 + row0)) * 4096 + (size_t)m0;
        for (int r = 0; r < 128; ++r) {
            float4* p = reinterpret_cast<float4*>(mm + base + (size_t)r * 4096);
            p[tid] = z; p[tid + 256] = z;
        }
    }
    {
        int lrow = tid >> 5, slot = tid & 31;
        for (int p = 0; p < 16; ++p) {
            int row  = p * 8 + lrow;
            float4 v = reinterpret_cast<const float4*>(
                           xd + ((size_t)(b * 4096 + row0 + row)) * 128)[slot];
            int ss = slot ^ (row & 31);
            *reinterpret_cast<float4*>(&Xs[row * 128 + (ss << 2)]) = v;
        }
    }
    float x2r[8];
    #pragma unroll
    for (int i = 0; i < 8; ++i) x2r[i] = ws[b * 4096 + row0 + ty * 8 + i];
    const float* y2g = ws + 16384 + b * 4096;
    float bv[8]; int bi[8];
    #pragma unroll
    for (int i = 0; i < 8; ++i) { bv[i] = 3.4e38f; bi[i] = 0; }
    __syncthreads();
    for (int tile = 0; tile < 16; ++tile) {
        const int mbase = m0 + tile * 128;
        {
            int lrow = tid >> 5, slot = tid & 31;
            for (int p = 0; p < 16; ++p) {
                int row  = p * 8 + lrow;
                float4 v = reinterpret_cast<const float4*>(
                               yd + ((size_t)(b * 4096 + mbase + row)) * 128)[slot];
                int ss = slot ^ (row & 31);
                *reinterpret_cast<float4*>(&Ys[row * 128 + (ss << 2)]) = v;
            }
        }
        __syncthreads();
        float acc[8][8];
        #pragma unroll
        for (int i = 0; i < 8; ++i)
            #pragma unroll
            for (int jj = 0; jj < 8; ++jj) acc[i][jj] = 0.0f;
        #pragma unroll 4
        for (int ks = 0; ks < 32; ++ks) {
            float4 bf[8];
            #pragma unroll
            for (int jj = 0; jj < 8; ++jj) {
                int c = jj * 16 + tx;
                bf[jj] = *reinterpret_cast<const float4*>(&Ys[c * 128 + ((ks ^ (c & 31)) << 2)]);
            }
            #pragma unroll
            for (int i = 0; i < 8; ++i) {
                int r = ty * 8 + i;
                float4 a = *reinterpret_cast<const float4*>(&Xs[r * 128 + ((ks ^ (r & 31)) << 2)]);
                #pragma unroll
                for (int jj = 0; jj < 8; ++jj) {
                    acc[i][jj] = fmaf(a.x, bf[jj].x, acc[i][jj]);
                    acc[i][jj] = fmaf(a.y, bf[jj].y, acc[i][jj]);
                    acc[i][jj] = fmaf(a.z, bf[jj].z, acc[i][jj]);
                    acc[i][jj] = fmaf(a.w, bf[jj].w, acc[i][jj]);
                }
            }
        }
        float y2v[8];
        #pragma unroll
        for (int jj = 0; jj < 8; ++jj) y2v[jj] = y2g[mbase + jj * 16 + tx];
        #pragma unroll
        for (int i = 0; i < 8; ++i) {
            int r = ty * 8 + i;
            const float* mr = mask + ((size_t)(b * 4096 + row0 + r)) * 4096;
            #pragma unroll
            for (int jj = 0; jj < 8; ++jj) {
                int   m  = mbase + jj * 16 + tx;
                float d2 = x2r[i] + y2v[jj] - 2.0f * acc[i][jj];
                float d  = sqrtf(fmaxf(d2, 0.0f)) * mr[m];
                if (d < bv[i]) { bv[i] = d; bi[i] = m; }
            }
        }
        __syncthreads();
    }
    float* candv = Xs;
    int*   candi = reinterpret_cast<int*>(Xs + 2048);
    #pragma unroll
    for (int i = 0; i < 8; ++i) {
        int r = ty * 8 + i;
        candv[r * 16 + tx] = bv[i];
        candi[r * 16 + tx] = bi[i];
    }
    __syncthreads();
    if (tid < 128) {
        int   r  = tid;
        float v  = candv[r * 16];
        int   ix = candi[r * 16];
        for (int t = 1; t < 16; ++t) {
            float v2 = candv[r * 16 + t];
            int   i2 = candi[r * 16 + t];
            if (v2 < v || (v2 == v && i2 < ix)) { v = v2; ix = i2; }
        }
        int grow = b * 4096 + row0 + r;
        pvals[grow * 2 + mh] = v;
        pidx [grow * 2 + mh] = ix;
    }
}

__global__ __launch_bounds__(256) void k_fin_fb(const float* __restrict__ pvals,
                                                const int* __restrict__ pidx,
                                                float* __restrict__ out) {
    int t = blockIdx.x * 256 + threadIdx.x;
    float v0 = pvals[t * 2], v1 = pvals[t * 2 + 1];
    int   i0 = pidx [t * 2], i1 = pidx [t * 2 + 1];
    bool take1 = (v1 < v0) || (v1 == v0 && i1 < i0);
    float v  = take1 ? v1 : v0;
    int   ix = take1 ? i1 : i0;
    out[67108864 + t]         = (float)ix;
    out[67108864 + 16384 + t] = v;
    out[(size_t)t * 4096 + (size_t)ix] = 1.0f;
}

extern "C" void kernel_launch(void* const* d_in, const int* in_sizes, int n_in,
                              void* d_out, int out_size, void* d_ws, size_t ws_size,
                              hipStream_t stream) {
    const float* xd   = (const float*)d_in[0];
    const float* yd   = (const float*)d_in[1];
    const float* mask = (const float*)d_in[2];
    float* out = (float*)d_out;
    float* wsf = (float*)d_ws;

    const size_t need = 131072 + 6 * PS * 2 + 524288;   // 25,821,184
    if (ws_size >= need) {
        unsigned short* pl = (unsigned short*)((char*)d_ws + 131072);
        float* pv = (float*)((char*)d_ws + 131072 + 6 * PS * 2);
        int*   pi = (int*)  ((char*)d_ws + 131072 + 6 * PS * 2 + 262144);
        k_prep <<<2048, 256, 0, stream>>>(xd, yd, pl, wsf);
        k_gemm <<<512,  256, 0, stream>>>(mask, wsf, pl, out, pv, pi);
        k_fin  <<<64,   256, 0, stream>>>(pv, pi, out);
    } else {
        float* pvals = wsf + 32768;
        int*   pidx  = (int*)(wsf + 65536);
        k_rowsq  <<<8192, 256, 0, stream>>>(xd, yd, wsf);
        k_main_fb<<<256,  256, 0, stream>>>(xd, yd, mask, wsf, pvals, pidx, out);
        k_fin_fb <<<64,   256, 0, stream>>>(pvals, pidx, out);
    }
}